// Round 11
// baseline (368.270 us; speedup 1.0000x reference)
//
#include <hip/hip_runtime.h>
#include <hip/hip_fp16.h>

#define NN 20480
#define EE 43008
#define BB 512
#define TT 3072

typedef _Float16 f16;
typedef _Float16 f16x8 __attribute__((ext_vector_type(8)));
typedef float f32x4 __attribute__((ext_vector_type(4)));

__device__ __forceinline__ float sigm(float x) { return 1.0f / (1.0f + __expf(-x)); }
__device__ __forceinline__ float tanh_f(float x) {
    float xc = fminf(fmaxf(x, -15.f), 15.f);
    float t = __expf(2.f * xc);
    return (t - 1.f) / (t + 1.f);
}

// ---------------- prep0: zero deg, lin0, edge nn1, packed-B builds, s2s transposes ----------
// B-frag pack convention (verified via qmtp): idx ((tile*2+c)*64+lane)*8+j holds B[k][n],
//   n = tile*16+(lane&15), k = c*32+((lane>>4)<<3)+j
__global__ void k_prep0(const float* __restrict__ x, const float* __restrict__ ea,
                        const float* __restrict__ l0w, const float* __restrict__ l0b,
                        const float* __restrict__ e1w, const float* __restrict__ e1b,
                        const float* __restrict__ e2w, const float* __restrict__ e2b,
                        const float* __restrict__ rootw,
                        const float* __restrict__ gwih, const float* __restrict__ gwhh,
                        const float* __restrict__ swih, const float* __restrict__ swhh,
                        const float* __restrict__ mwih,
                        float* __restrict__ feat, f16* __restrict__ feat16, f16* __restrict__ ew16,
                        f16* __restrict__ qmtp, float* __restrict__ deg,
                        f16* __restrict__ rootp, f16* __restrict__ wihp, f16* __restrict__ whhp,
                        float* __restrict__ s2sihT, float* __restrict__ s2shhT,
                        float* __restrict__ memihT)
{
    const int S0 = NN;
    const int S1 = S0 + NN * 64;
    const int S2 = S1 + EE * 64;
    const int S3 = S2 + 130 * 256 * 8;
    const int S4 = S3 + 4096;
    const int S5 = S4 + 12288;
    const int S6 = S5 + 12288;
    const int S7 = S6 + 128 * 256;
    const int S8 = S7 + 64 * 256;
    const int S9 = S8 + 128 * 256;
    for (int idx = blockIdx.x * blockDim.x + threadIdx.x; idx < S9; idx += gridDim.x * blockDim.x) {
        if (idx < S0) {
            deg[idx] = 0.f;
        } else if (idx < S1) {
            int t = idx - S0; int n = t >> 6, o = t & 63;
            float v = l0b[o] + x[n * 3] * l0w[o * 3] + x[n * 3 + 1] * l0w[o * 3 + 1] + x[n * 3 + 2] * l0w[o * 3 + 2];
            v = fmaxf(v, 0.f);
            feat[t] = v; feat16[t] = (f16)v;
        } else if (idx < S2) {
            int t = idx - S1; int e = t >> 6, o = t & 63;
            float acc = e1b[o];
#pragma unroll
            for (int j = 0; j < 6; ++j) acc += ea[e * 6 + j] * e1w[o * 6 + j];
            ew16[t] = (f16)fmaxf(acc, 0.f);
        } else if (idx < S3) {
            int t = idx - S2;                 // [0, 266240)
            int j = t & 7;
            int lane = (t >> 3) & 63;
            int cc = t >> 9;                  // c*4 + ct, 0..519
            int c = cc >> 2, ct = cc & 3;
            int n = (ct << 4) | (lane & 15);
            int col = c * 32 + ((lane >> 4) << 3) + j;
            float v;
            if (col < 4096) v = e2w[(((col >> 6) << 6) + n) * 64 + (col & 63)];
            else            v = e2b[(col - 4096) * 64 + n];
            qmtp[t] = (f16)v;
        } else if (idx < S4) {
            int t = idx - S3; int j = t & 7; int lane = (t >> 3) & 63;
            int cc = t >> 9;                  // 0..7
            int ct = cc >> 1, c = cc & 1;
            int n = ct * 16 + (lane & 15);
            int k = c * 32 + ((lane >> 4) << 3) + j;
            rootp[t] = (f16)rootw[k * 64 + n];
        } else if (idx < S5) {
            int t = idx - S4; int j = t & 7; int lane = (t >> 3) & 63;
            int cc = t >> 9;                  // 0..23
            int gct = cc >> 1, c = cc & 1;
            int g = gct * 16 + (lane & 15);
            int k = c * 32 + ((lane >> 4) << 3) + j;
            wihp[t] = (f16)gwih[g * 64 + k];
        } else if (idx < S6) {
            int t = idx - S5; int j = t & 7; int lane = (t >> 3) & 63;
            int cc = t >> 9;
            int gct = cc >> 1, c = cc & 1;
            int g = gct * 16 + (lane & 15);
            int k = c * 32 + ((lane >> 4) << 3) + j;
            whhp[t] = (f16)gwhh[g * 64 + k];
        }
        else if (idx < S7)   { int t = idx - S6; int k = t >> 8, j = t & 255; s2sihT[t] = swih[j * 128 + k]; }
        else if (idx < S8)   { int t = idx - S7; int k = t >> 8, j = t & 255; s2shhT[t] = swhh[j * 64 + k]; }
        else                 { int t = idx - S8; int k = t >> 8, j = t & 255; memihT[t] = mwih[j * 128 + k]; }
    }
}

// ---------------- prep1: degree ----------------
__global__ void k_prep1(const int* __restrict__ dstp, float* __restrict__ deg)
{
    int e = blockIdx.x * blockDim.x + threadIdx.x;
    if (e < EE) atomicAdd(&deg[dstp[e]], 1.0f);
}

// ---------------- scan: rowptr = exclusive prefix of deg; zero fill ----------------
__global__ __launch_bounds__(1024) void k_scan(const float* __restrict__ deg,
                                               int* __restrict__ rowptr, int* __restrict__ fill)
{
    __shared__ int part[1024];
    const int t = threadIdx.x;
    const int base = t * 20;
    int local[20];
    int s = 0;
#pragma unroll
    for (int j = 0; j < 20; ++j) { local[j] = s; s += (int)deg[base + j]; }
    part[t] = s;
    __syncthreads();
    for (int off = 1; off < 1024; off <<= 1) {
        int u = (t >= off) ? part[t - off] : 0;
        __syncthreads();
        part[t] += u;
        __syncthreads();
    }
    const int coff = part[t] - s;   // exclusive chunk offset
#pragma unroll
    for (int j = 0; j < 20; ++j) { rowptr[base + j] = coff + local[j]; fill[base + j] = 0; }
    if (t == 1023) rowptr[NN] = part[1023];
}

// ---------------- fill: CSR edge lists ----------------
__global__ void k_fill(const int* __restrict__ dstp, const int* __restrict__ rowptr,
                       int* __restrict__ fill, int* __restrict__ eidx)
{
    int e = blockIdx.x * blockDim.x + threadIdx.x;
    if (e < EE) {
        int d = dstp[e];
        int slot = atomicAdd(&fill[d], 1);
        eidx[rowptr[d] + slot] = e;
    }
}

// ---------------- msg GEMM: 64 edges/block, 4 waves = K-quarters, each 64x64 output ----
// wave kp: i in [kp*16, kp*16+16); per i-step: build a0/a1 per rg, each feeds 4 ct MFMAs.
// kp1..3 write f32 partials to LDS; kp0 sums and writes msg. Bias pair handled by kp3.
__global__ __launch_bounds__(256, 2) void k_msg(const f16* __restrict__ feat16, const f16* __restrict__ ew16,
                                                const f16* __restrict__ qmtp,
                                                const int* __restrict__ srcp,
                                                float* __restrict__ msg)
{
    __shared__ f16 s_lds[64 * 64];
    __shared__ f16 w_lds[64 * 64];
    __shared__ float cmb[3][64][68];
    const int tid = threadIdx.x;
    const int e0 = blockIdx.x * 64;
    {
        int row = tid >> 2, q = tid & 3;
        int sn = srcp[e0 + row];
        const uint4* gs = (const uint4*)(feat16 + (size_t)sn * 64 + q * 16);
        const uint4* gw = (const uint4*)(ew16 + (size_t)(e0 + row) * 64 + q * 16);
        uint4 s0v = gs[0], s1v = gs[1];
        uint4 w0v = gw[0], w1v = gw[1];
        char* sbw = (char*)s_lds;
        char* wbw = (char*)w_lds;
        int swz = (row & 7) << 4;
        *(uint4*)(sbw + row * 128 + ((q * 32) ^ swz)) = s0v;
        *(uint4*)(sbw + row * 128 + ((q * 32 + 16) ^ swz)) = s1v;
        *(uint4*)(wbw + row * 128 + ((q * 32) ^ swz)) = w0v;
        *(uint4*)(wbw + row * 128 + ((q * 32 + 16) ^ swz)) = w1v;
    }
    __syncthreads();
    const int kp = tid >> 6, l = tid & 63;
    const int lh = l >> 4, ll = l & 15;
    const char* sb = (const char*)s_lds;
    const char* wb = (const char*)w_lds;
    int rowv[4], swzv[4];
#pragma unroll
    for (int rg = 0; rg < 4; ++rg) { rowv[rg] = rg * 16 + ll; swzv[rg] = (rowv[rg] & 7) << 4; }
    // loop-invariant ew fragments (k64-half 0/1)
    f16x8 wf[4][2];
#pragma unroll
    for (int rg = 0; rg < 4; ++rg) {
        wf[rg][0] = *(const f16x8*)(wb + rowv[rg] * 128 + ((lh * 16) ^ swzv[rg]));
        wf[rg][1] = *(const f16x8*)(wb + rowv[rg] * 128 + ((64 + lh * 16) ^ swzv[rg]));
    }
    const int i0 = kp * 16;
    // s-scalar batches for this wave's 16 i-values
    f16x8 sc0[4], sc1[4];
#pragma unroll
    for (int rg = 0; rg < 4; ++rg) {
        sc0[rg] = *(const f16x8*)(sb + rowv[rg] * 128 + ((i0 * 2) ^ swzv[rg]));
        sc1[rg] = *(const f16x8*)(sb + rowv[rg] * 128 + ((i0 * 2 + 16) ^ swzv[rg]));
    }
    const f16x8* base = (const f16x8*)qmtp + l;
    f32x4 acc[4][4] = {};
    f16x8 SA[8], SB[8];
    auto issue = [&](f16x8 (&S)[8], int i) {
#pragma unroll
        for (int ab = 0; ab < 2; ++ab)
#pragma unroll
            for (int ct = 0; ct < 4; ++ct)
                S[ab * 4 + ct] = base[((2 * i + ab) * 4 + ct) * 64];
    };
    issue(SA, i0);
    issue(SB, i0 + 1);
#pragma unroll
    for (int pp = 0; pp < 16; pp += 2) {
        // ---- use SA (i = i0+pp) ----
        __builtin_amdgcn_s_setprio(1);
#pragma unroll
        for (int rg = 0; rg < 4; ++rg) {
            f16 s = (pp < 8) ? sc0[rg][pp] : sc1[rg][pp - 8];
            f16x8 a0, a1;
#pragma unroll
            for (int j8 = 0; j8 < 8; ++j8) { a0[j8] = wf[rg][0][j8] * s; a1[j8] = wf[rg][1][j8] * s; }
#pragma unroll
            for (int ct = 0; ct < 4; ++ct) {
                acc[rg][ct] = __builtin_amdgcn_mfma_f32_16x16x32_f16(a0, SA[ct], acc[rg][ct], 0, 0, 0);
                acc[rg][ct] = __builtin_amdgcn_mfma_f32_16x16x32_f16(a1, SA[4 + ct], acc[rg][ct], 0, 0, 0);
            }
        }
        __builtin_amdgcn_s_setprio(0);
        issue(SA, i0 + pp + 2);
        // ---- use SB (i = i0+pp+1) ----
        __builtin_amdgcn_s_setprio(1);
#pragma unroll
        for (int rg = 0; rg < 4; ++rg) {
            f16 s = (pp + 1 < 8) ? sc0[rg][pp + 1] : sc1[rg][pp + 1 - 8];
            f16x8 a0, a1;
#pragma unroll
            for (int j8 = 0; j8 < 8; ++j8) { a0[j8] = wf[rg][0][j8] * s; a1[j8] = wf[rg][1][j8] * s; }
#pragma unroll
            for (int ct = 0; ct < 4; ++ct) {
                acc[rg][ct] = __builtin_amdgcn_mfma_f32_16x16x32_f16(a0, SB[ct], acc[rg][ct], 0, 0, 0);
                acc[rg][ct] = __builtin_amdgcn_mfma_f32_16x16x32_f16(a1, SB[4 + ct], acc[rg][ct], 0, 0, 0);
            }
        }
        __builtin_amdgcn_s_setprio(0);
        issue(SB, i0 + pp + 3);
    }
    if (kp == 3) {
        // bias pair c=128,129 (i=64): A = feat fragments directly
        f16x8 BBf[8];
        issue(BBf, 64);
#pragma unroll
        for (int rg = 0; rg < 4; ++rg) {
            f16x8 sf0 = *(const f16x8*)(sb + rowv[rg] * 128 + ((lh * 16) ^ swzv[rg]));
            f16x8 sf1 = *(const f16x8*)(sb + rowv[rg] * 128 + ((64 + lh * 16) ^ swzv[rg]));
#pragma unroll
            for (int ct = 0; ct < 4; ++ct) {
                acc[rg][ct] = __builtin_amdgcn_mfma_f32_16x16x32_f16(sf0, BBf[ct], acc[rg][ct], 0, 0, 0);
                acc[rg][ct] = __builtin_amdgcn_mfma_f32_16x16x32_f16(sf1, BBf[4 + ct], acc[rg][ct], 0, 0, 0);
            }
        }
    }
    if (kp > 0) {
#pragma unroll
        for (int rg = 0; rg < 4; ++rg)
#pragma unroll
            for (int ct = 0; ct < 4; ++ct)
#pragma unroll
                for (int q = 0; q < 4; ++q)
                    cmb[kp - 1][rg * 16 + lh * 4 + q][ct * 16 + ll] = acc[rg][ct][q];
    }
    __syncthreads();
    if (kp == 0) {
#pragma unroll
        for (int rg = 0; rg < 4; ++rg)
#pragma unroll
            for (int q = 0; q < 4; ++q) {
                int r = rg * 16 + lh * 4 + q;
#pragma unroll
                for (int ct = 0; ct < 4; ++ct) {
                    int c = ct * 16 + ll;
                    float v = acc[rg][ct][q] + cmb[0][r][c] + cmb[1][r][c] + cmb[2][r][c];
                    msg[(size_t)(e0 + r) * 64 + c] = v;
                }
            }
    }
}

// ---------------- node update: 16 nodes/block, 4 waves; parallel CSR gather + MFMA GEMMs ----
__global__ __launch_bounds__(256) void k_node(float* __restrict__ feat, f16* __restrict__ feat16,
        const float* __restrict__ msg, const int* __restrict__ rowptr,
        const int* __restrict__ eidx, const float* __restrict__ deg,
        const f16* __restrict__ rootp, const f16* __restrict__ wihp, const f16* __restrict__ whhp,
        const float* __restrict__ conv_b, const float* __restrict__ bih, const float* __restrict__ bhh)
{
    __shared__ f16 h16[16 * 64];
    __shared__ f16 m16[16 * 64];
    __shared__ float aggm[16][68];
    const int tid = threadIdx.x;
    const int wv = tid >> 6, l = tid & 63;
    const int lh = l >> 4, ll = l & 15;
    const int nb = blockIdx.x * 16;
    char* hb = (char*)h16;
    char* mb = (char*)m16;
    // ---- gather: thread (wv,l) gathers 4 nodes' column l (rowptr/eidx wave-uniform) ----
#pragma unroll
    for (int i = 0; i < 4; ++i) {
        int nd = wv * 4 + i;
        int n = nb + nd;
        float hv = feat[(size_t)n * 64 + l];
        int r0 = rowptr[n], r1 = rowptr[n + 1];
        float a = 0.f;
        for (int r = r0; r < r1; ++r) a += msg[(size_t)eidx[r] * 64 + l];
        aggm[nd][l] = a;
        int swz = (nd & 7) << 4;
        *(f16*)(hb + nd * 128 + ((l * 2) ^ swz)) = (f16)hv;
    }
    __syncthreads();
    // ---- A-fragments of h (lane: row = ll, k = lh*8+j [+32 for frag 1]) ----
    const int rsw = (ll & 7) << 4;
    f16x8 hA0 = *(const f16x8*)(hb + ll * 128 + ((lh * 16) ^ rsw));
    f16x8 hA1 = *(const f16x8*)(hb + ll * 128 + ((64 + lh * 16) ^ rsw));
    const int col = wv * 16 + ll;
    float invd[4];
#pragma unroll
    for (int q = 0; q < 4; ++q) invd[q] = 1.0f / fmaxf(deg[nb + lh * 4 + q], 1.0f);
    // ---- root GEMM (wave wv -> col tile wv) + scatter-mean epilogue -> m16 ----
    {
        f16x8 b0 = *(const f16x8*)(rootp + ((size_t)(wv * 2 + 0) * 64 + l) * 8);
        f16x8 b1 = *(const f16x8*)(rootp + ((size_t)(wv * 2 + 1) * 64 + l) * 8);
        f32x4 acc = {};
        acc = __builtin_amdgcn_mfma_f32_16x16x32_f16(hA0, b0, acc, 0, 0, 0);
        acc = __builtin_amdgcn_mfma_f32_16x16x32_f16(hA1, b1, acc, 0, 0, 0);
        float cb = conv_b[col];
#pragma unroll
        for (int q = 0; q < 4; ++q) {
            int row = lh * 4 + q;
            float mv = fmaxf(aggm[row][col] * invd[q] + acc[q] + cb, 0.f);
            int swz = (row & 7) << 4;
            *(f16*)(mb + row * 128 + ((col * 2) ^ swz)) = (f16)mv;
        }
    }
    __syncthreads();
    f16x8 mA0 = *(const f16x8*)(mb + ll * 128 + ((lh * 16) ^ rsw));
    f16x8 mA1 = *(const f16x8*)(mb + ll * 128 + ((64 + lh * 16) ^ rsw));
    // ---- gate GEMMs: wave wv computes gate-tiles {wv, 4+wv, 8+wv} ----
    f32x4 gi0 = {}, gi1 = {}, gi2 = {}, gh0 = {}, gh1 = {}, gh2 = {};
    {
        f16x8 b;
        b = *(const f16x8*)(wihp + ((size_t)((wv + 0) * 2 + 0) * 64 + l) * 8);
        gi0 = __builtin_amdgcn_mfma_f32_16x16x32_f16(mA0, b, gi0, 0, 0, 0);
        b = *(const f16x8*)(wihp + ((size_t)((wv + 0) * 2 + 1) * 64 + l) * 8);
        gi0 = __builtin_amdgcn_mfma_f32_16x16x32_f16(mA1, b, gi0, 0, 0, 0);
        b = *(const f16x8*)(wihp + ((size_t)((wv + 4) * 2 + 0) * 64 + l) * 8);
        gi1 = __builtin_amdgcn_mfma_f32_16x16x32_f16(mA0, b, gi1, 0, 0, 0);
        b = *(const f16x8*)(wihp + ((size_t)((wv + 4) * 2 + 1) * 64 + l) * 8);
        gi1 = __builtin_amdgcn_mfma_f32_16x16x32_f16(mA1, b, gi1, 0, 0, 0);
        b = *(const f16x8*)(wihp + ((size_t)((wv + 8) * 2 + 0) * 64 + l) * 8);
        gi2 = __builtin_amdgcn_mfma_f32_16x16x32_f16(mA0, b, gi2, 0, 0, 0);
        b = *(const f16x8*)(wihp + ((size_t)((wv + 8) * 2 + 1) * 64 + l) * 8);
        gi2 = __builtin_amdgcn_mfma_f32_16x16x32_f16(mA1, b, gi2, 0, 0, 0);
        b = *(const f16x8*)(whhp + ((size_t)((wv + 0) * 2 + 0) * 64 + l) * 8);
        gh0 = __builtin_amdgcn_mfma_f32_16x16x32_f16(hA0, b, gh0, 0, 0, 0);
        b = *(const f16x8*)(whhp + ((size_t)((wv + 0) * 2 + 1) * 64 + l) * 8);
        gh0 = __builtin_amdgcn_mfma_f32_16x16x32_f16(hA1, b, gh0, 0, 0, 0);
        b = *(const f16x8*)(whhp + ((size_t)((wv + 4) * 2 + 0) * 64 + l) * 8);
        gh1 = __builtin_amdgcn_mfma_f32_16x16x32_f16(hA0, b, gh1, 0, 0, 0);
        b = *(const f16x8*)(whhp + ((size_t)((wv + 4) * 2 + 1) * 64 + l) * 8);
        gh1 = __builtin_amdgcn_mfma_f32_16x16x32_f16(hA1, b, gh1, 0, 0, 0);
        b = *(const f16x8*)(whhp + ((size_t)((wv + 8) * 2 + 0) * 64 + l) * 8);
        gh2 = __builtin_amdgcn_mfma_f32_16x16x32_f16(hA0, b, gh2, 0, 0, 0);
        b = *(const f16x8*)(whhp + ((size_t)((wv + 8) * 2 + 1) * 64 + l) * 8);
        gh2 = __builtin_amdgcn_mfma_f32_16x16x32_f16(hA1, b, gh2, 0, 0, 0);
    }
    // ---- GRU elementwise + store (wave writes rows lh*4+q, col = wv*16+ll) ----
    {
        float bi0 = bih[col], bi1 = bih[64 + col], bi2 = bih[128 + col];
        float bh0 = bhh[col], bh1 = bhh[64 + col], bh2 = bhh[128 + col];
#pragma unroll
        for (int q = 0; q < 4; ++q) {
            int n = nb + lh * 4 + q;
            float r = sigm(gi0[q] + bi0 + gh0[q] + bh0);
            float z = sigm(gi1[q] + bi1 + gh1[q] + bh1);
            float nn2 = tanh_f(gi2[q] + bi2 + r * (gh2[q] + bh2));
            float hold = feat[(size_t)n * 64 + col];
            float hn = (1.f - z) * nn2 + z * hold;
            feat[(size_t)n * 64 + col] = hn;
            feat16[(size_t)n * 64 + col] = (f16)hn;
        }
    }
}

// ---------------- Set2Set (6 steps) + memory LSTM; 2 graphs/block, 512 threads, K-split gates ----
__global__ __launch_bounds__(512) void k_s2s(const float* __restrict__ feat,
                                             const float* __restrict__ s2sihT, const float* __restrict__ s2shhT,
                                             const float* __restrict__ sbih, const float* __restrict__ sbhh,
                                             const float* __restrict__ memihT,
                                             const float* __restrict__ mbih, const float* __restrict__ mbhh,
                                             float* __restrict__ lstm_out, float* __restrict__ dout)
{
    __shared__ float ft[2][64][49];     // feat transposed: ft[g][o][row]; 49 stride -> conflict-free
    __shared__ float qs[2][128];
    __shared__ float hh[2][64];
    __shared__ float cc[2][64];
    __shared__ float qv[2][64];
    __shared__ float g0p[2][256];       // gate partials, half 0
    __shared__ float g1p[2][256];       // gate partials, half 1
    const int t = threadIdx.x;
    const int g0 = blockIdx.x * 2;
    for (int i = t; i < 2 * 40 * 64; i += 512) {
        int g = i / 2560;
        int rem = i - g * 2560;
        int row = rem >> 6, o = rem & 63;
        ft[g][o][row] = feat[((size_t)(g0 + g) * 40 + row) * 64 + o];
    }
    if (t < 256) qs[t >> 7][t & 127] = 0.f;
    if (t < 128) { hh[t >> 6][t & 63] = 0.f; cc[t >> 6][t & 63] = 0.f; }
    __syncthreads();
    const int jj = t & 255;              // gate index
    const int half = t >> 8;             // K-split half
    const int gg = t >> 6, gl = t & 63;  // cell/attention mapping (t < 128)
    const float b_s = sbih[jj] + sbhh[jj];
    const float b_m = mbih[jj] + mbhh[jj];
    for (int step = 0; step < 7; ++step) {
        const bool mem = (step == 6);
        {
            float a0, a1;
            if (!mem) {
                if (half == 0) {
                    a0 = b_s; a1 = b_s;
#pragma unroll 16
                    for (int k = 0; k < 96; ++k) {
                        float w = s2sihT[k * 256 + jj];
                        a0 += qs[0][k] * w;
                        a1 += qs[1][k] * w;
                    }
                } else {
                    a0 = 0.f; a1 = 0.f;
#pragma unroll 16
                    for (int k = 96; k < 128; ++k) {
                        float w = s2sihT[k * 256 + jj];
                        a0 += qs[0][k] * w;
                        a1 += qs[1][k] * w;
                    }
#pragma unroll 16
                    for (int k = 0; k < 64; ++k) {
                        float w = s2shhT[k * 256 + jj];
                        a0 += hh[0][k] * w;
                        a1 += hh[1][k] * w;
                    }
                }
            } else {
                if (half == 0) {
                    a0 = b_m; a1 = b_m;
#pragma unroll 16
                    for (int k = 0; k < 64; ++k) {
                        float w = memihT[k * 256 + jj];
                        a0 += qs[0][k] * w;
                        a1 += qs[1][k] * w;
                    }
                } else {
                    a0 = 0.f; a1 = 0.f;
#pragma unroll 16
                    for (int k = 64; k < 128; ++k) {
                        float w = memihT[k * 256 + jj];
                        a0 += qs[0][k] * w;
                        a1 += qs[1][k] * w;
                    }
                }
            }
            if (half == 0) { g0p[0][jj] = a0; g0p[1][jj] = a1; }
            else           { g1p[0][jj] = a0; g1p[1][jj] = a1; }
        }
        __syncthreads();
        if (t < 128) {
            float ii = sigm(g0p[gg][gl]        + g1p[gg][gl]);
            float ff = sigm(g0p[gg][64 + gl]   + g1p[gg][64 + gl]);
            float g2 = tanh_f(g0p[gg][128 + gl] + g1p[gg][128 + gl]);
            float oo = sigm(g0p[gg][192 + gl]  + g1p[gg][192 + gl]);
            float cprev = mem ? 0.f : cc[gg][gl];
            float c2 = ff * cprev + ii * g2;
            float h2 = oo * tanh_f(c2);
            if (!mem) {
                cc[gg][gl] = c2; hh[gg][gl] = h2;
                qv[gg][gl] = h2; qs[gg][gl] = h2;
                const int g = gg, l = gl;
                float e = -1e30f;
                if (l < 40) {
                    float s = 0.f;
                    for (int o = 0; o < 64; ++o) s += ft[g][o][l] * qv[g][o];
                    e = s;
                }
                float emax = e;
#pragma unroll
                for (int off = 32; off; off >>= 1) emax = fmaxf(emax, __shfl_xor(emax, off));
                float av = (l < 40) ? __expf(e - emax) : 0.f;
                float asum = av;
#pragma unroll
                for (int off = 32; off; off >>= 1) asum += __shfl_xor(asum, off);
                av /= asum;
                float r = 0.f;
                for (int nd = 0; nd < 40; ++nd) r += __shfl(av, nd) * ft[g][l][nd];
                qs[g][64 + l] = r;
            } else {
                int gidx = g0 + gg;
                lstm_out[(size_t)gidx * 64 + gl] = h2;
                dout[18432 + (size_t)gidx * 64 + gl] = h2;
                dout[18432 + 32768 + (size_t)gidx * 64 + gl] = c2;
            }
        }
        __syncthreads();
    }
}

// ---------------- final MLP with the reference's (d,a,s) scramble ----------------
__global__ __launch_bounds__(256) void k_final(const float* __restrict__ feat,
                                               const float* __restrict__ lstm_out,
                                               const int* __restrict__ nrbidx, const int* __restrict__ nonring,
                                               const float* __restrict__ l1w, const float* __restrict__ l1b,
                                               const float* __restrict__ l2w, const float* __restrict__ l2b,
                                               float* __restrict__ dout)
{
    __shared__ float z_lds[4][320];
    __shared__ float y_lds[4][64];
    const int wv = threadIdx.x >> 6, l = threadIdx.x & 63;
    const int r = blockIdx.x * 4 + wv;
    const int b = r / 6, rr = r - b * 6;
#pragma unroll
    for (int p = 0; p < 5; ++p) {
        int c = p * 64 + l;
        int f2 = rr * 320 + c;
        int d = f2 / 30;
        int rem = f2 - d * 30;
        int a = rem / 5;
        int s = rem - a * 5;
        float v;
        if (s == 0) v = lstm_out[(size_t)nrbidx[b * 6 + a] * 64 + d];
        else {
            int atom = nonring[b * 24 + (s - 1) * 6 + a];
            v = feat[(size_t)atom * 64 + d];
        }
        z_lds[wv][c] = v;
    }
    __syncthreads();
    {
        float acc = l1b[l];
        const float4* wr = (const float4*)(l1w + (size_t)l * 320);
        const float4* zr = (const float4*)(z_lds[wv]);
        for (int c4 = 0; c4 < 80; ++c4) {
            float4 w4 = wr[c4]; float4 z4 = zr[c4];
            acc += w4.x * z4.x + w4.y * z4.y + w4.z * z4.z + w4.w * z4.w;
        }
        y_lds[wv][l] = fmaxf(acc, 0.f);
    }
    __syncthreads();
    if (l < 6) {
        float acc = l2b[l];
        const float* yr = y_lds[wv];
        const float* w2 = l2w + l * 64;
        for (int o = 0; o < 64; ++o) acc += yr[o] * w2[o];
        dout[b * 36 + rr * 6 + l] = acc;
    }
}

extern "C" void kernel_launch(void* const* d_in, const int* in_sizes, int n_in,
                              void* d_out, int out_size, void* d_ws, size_t ws_size,
                              hipStream_t stream)
{
    const float* x    = (const float*)d_in[0];
    const float* ea   = (const float*)d_in[1];
    const int*   ei   = (const int*)d_in[2];
    const int*   nrb  = (const int*)d_in[4];
    const int*   nonr = (const int*)d_in[5];
    const float* l0w  = (const float*)d_in[6];  const float* l0b = (const float*)d_in[7];
    const float* e1w  = (const float*)d_in[8];  const float* e1b = (const float*)d_in[9];
    const float* e2w  = (const float*)d_in[10]; const float* e2b = (const float*)d_in[11];
    const float* rootw= (const float*)d_in[12]; const float* convb = (const float*)d_in[13];
    const float* gwih = (const float*)d_in[14]; const float* gbih = (const float*)d_in[15];
    const float* gwhh = (const float*)d_in[16]; const float* gbhh = (const float*)d_in[17];
    const float* swih = (const float*)d_in[18]; const float* sbih = (const float*)d_in[19];
    const float* swhh = (const float*)d_in[20]; const float* sbhh = (const float*)d_in[21];
    const float* mwih = (const float*)d_in[22]; const float* mbih = (const float*)d_in[23];
    const float* mbhh = (const float*)d_in[25];
    const float* l1w  = (const float*)d_in[26]; const float* l1b = (const float*)d_in[27];
    const float* l2w  = (const float*)d_in[28]; const float* l2b = (const float*)d_in[29];
    const int* srcp = ei;
    const int* dstp = ei + EE;
    float* dout = (float*)d_out;

    char* w = (char*)d_ws;
    size_t off = 0;
    auto alloc = [&](size_t bytes) -> void* {
        off = (off + 255) & ~(size_t)255;
        void* p = w + off;
        off += bytes;
        return p;
    };
    float* feat    = (float*)alloc((size_t)NN * 64 * 4);
    f16*   feat16  = (f16*)alloc((size_t)NN * 64 * 2);
    f16*   ew16    = (f16*)alloc((size_t)EE * 64 * 2);
    f16*   qmtp    = (f16*)alloc((size_t)136 * 256 * 8 * 2);   // padded past c=133 prefetch overrun
    float* msg     = (float*)alloc((size_t)EE * 64 * 4);
    float* deg     = (float*)alloc((size_t)NN * 4);
    int*   rowptr  = (int*)alloc((size_t)(NN + 1) * 4);
    int*   fill    = (int*)alloc((size_t)NN * 4);
    int*   eidx    = (int*)alloc((size_t)EE * 4);
    f16*   rootp   = (f16*)alloc((size_t)4096 * 2);
    f16*   wihp    = (f16*)alloc((size_t)12288 * 2);
    f16*   whhp    = (f16*)alloc((size_t)12288 * 2);
    float* s2sihT  = (float*)alloc((size_t)128 * 256 * 4);
    float* s2shhT  = (float*)alloc((size_t)64 * 256 * 4);
    float* memihT  = (float*)alloc((size_t)128 * 256 * 4);
    float* lstmo   = (float*)alloc((size_t)BB * 64 * 4);
    (void)ws_size; (void)in_sizes; (void)n_in; (void)out_size;

    hipLaunchKernelGGL(k_prep0, dim3(1024), dim3(256), 0, stream,
                       x, ea, l0w, l0b, e1w, e1b, e2w, e2b, rootw, gwih, gwhh, swih, swhh, mwih,
                       feat, feat16, ew16, qmtp, deg, rootp, wihp, whhp, s2sihT, s2shhT, memihT);
    hipLaunchKernelGGL(k_prep1, dim3(EE / 256), dim3(256), 0, stream, dstp, deg);
    hipLaunchKernelGGL(k_scan, dim3(1), dim3(1024), 0, stream, deg, rowptr, fill);
    hipLaunchKernelGGL(k_fill, dim3(EE / 256), dim3(256), 0, stream, dstp, rowptr, fill, eidx);
    for (int it = 0; it < 6; ++it) {
        hipLaunchKernelGGL(k_msg, dim3(EE / 64), dim3(256), 0, stream,
                           feat16, ew16, qmtp, srcp, msg);
        hipLaunchKernelGGL(k_node, dim3(NN / 16), dim3(256), 0, stream,
                           feat, feat16, msg, rowptr, eidx, deg, rootp, wihp, whhp, convb, gbih, gbhh);
    }
    hipLaunchKernelGGL(k_s2s, dim3(BB / 2), dim3(512), 0, stream,
                       feat, s2sihT, s2shhT, sbih, sbhh, memihT, mbih, mbhh, lstmo, dout);
    hipLaunchKernelGGL(k_final, dim3(TT / 4), dim3(256), 0, stream,
                       feat, lstmo, nrb, nonr, l1w, l1b, l2w, l2b, dout);
}

// Round 12
// 338.966 us; speedup vs baseline: 1.0865x; 1.0865x over previous
//
#include <hip/hip_runtime.h>
#include <hip/hip_fp16.h>

#define NN 20480
#define EE 43008
#define BB 512
#define TT 3072

typedef _Float16 f16;
typedef _Float16 f16x8 __attribute__((ext_vector_type(8)));
typedef float f32x4 __attribute__((ext_vector_type(4)));

__device__ __forceinline__ float sigm(float x) { return 1.0f / (1.0f + __expf(-x)); }
__device__ __forceinline__ float tanh_f(float x) {
    float xc = fminf(fmaxf(x, -15.f), 15.f);
    float t = __expf(2.f * xc);
    return (t - 1.f) / (t + 1.f);
}

// ---------------- prep0: zero deg, lin0, edge nn1, packed-B builds, s2s transposes ----------
__global__ void k_prep0(const float* __restrict__ x, const float* __restrict__ ea,
                        const float* __restrict__ l0w, const float* __restrict__ l0b,
                        const float* __restrict__ e1w, const float* __restrict__ e1b,
                        const float* __restrict__ e2w, const float* __restrict__ e2b,
                        const float* __restrict__ rootw,
                        const float* __restrict__ gwih, const float* __restrict__ gwhh,
                        const float* __restrict__ swih, const float* __restrict__ swhh,
                        const float* __restrict__ mwih,
                        float* __restrict__ feat, f16* __restrict__ feat16, f16* __restrict__ ew16,
                        f16* __restrict__ qmtp, float* __restrict__ deg,
                        f16* __restrict__ rootp, f16* __restrict__ wihp, f16* __restrict__ whhp,
                        float* __restrict__ s2sihT, float* __restrict__ s2shhT,
                        float* __restrict__ memihT)
{
    const int S0 = NN;
    const int S1 = S0 + NN * 64;
    const int S2 = S1 + EE * 64;
    const int S3 = S2 + 130 * 256 * 8;
    const int S4 = S3 + 4096;
    const int S5 = S4 + 12288;
    const int S6 = S5 + 12288;
    const int S7 = S6 + 128 * 256;
    const int S8 = S7 + 64 * 256;
    const int S9 = S8 + 128 * 256;
    for (int idx = blockIdx.x * blockDim.x + threadIdx.x; idx < S9; idx += gridDim.x * blockDim.x) {
        if (idx < S0) {
            deg[idx] = 0.f;
        } else if (idx < S1) {
            int t = idx - S0; int n = t >> 6, o = t & 63;
            float v = l0b[o] + x[n * 3] * l0w[o * 3] + x[n * 3 + 1] * l0w[o * 3 + 1] + x[n * 3 + 2] * l0w[o * 3 + 2];
            v = fmaxf(v, 0.f);
            feat[t] = v; feat16[t] = (f16)v;
        } else if (idx < S2) {
            int t = idx - S1; int e = t >> 6, o = t & 63;
            float acc = e1b[o];
#pragma unroll
            for (int j = 0; j < 6; ++j) acc += ea[e * 6 + j] * e1w[o * 6 + j];
            ew16[t] = (f16)fmaxf(acc, 0.f);
        } else if (idx < S3) {
            int t = idx - S2;
            int j = t & 7;
            int lane = (t >> 3) & 63;
            int cc = t >> 9;
            int c = cc >> 2, ct = cc & 3;
            int n = (ct << 4) | (lane & 15);
            int col = c * 32 + ((lane >> 4) << 3) + j;
            float v;
            if (col < 4096) v = e2w[(((col >> 6) << 6) + n) * 64 + (col & 63)];
            else            v = e2b[(col - 4096) * 64 + n];
            qmtp[t] = (f16)v;
        } else if (idx < S4) {
            int t = idx - S3; int j = t & 7; int lane = (t >> 3) & 63;
            int cc = t >> 9;
            int ct = cc >> 1, c = cc & 1;
            int n = ct * 16 + (lane & 15);
            int k = c * 32 + ((lane >> 4) << 3) + j;
            rootp[t] = (f16)rootw[k * 64 + n];
        } else if (idx < S5) {
            int t = idx - S4; int j = t & 7; int lane = (t >> 3) & 63;
            int cc = t >> 9;
            int gct = cc >> 1, c = cc & 1;
            int g = gct * 16 + (lane & 15);
            int k = c * 32 + ((lane >> 4) << 3) + j;
            wihp[t] = (f16)gwih[g * 64 + k];
        } else if (idx < S6) {
            int t = idx - S5; int j = t & 7; int lane = (t >> 3) & 63;
            int cc = t >> 9;
            int gct = cc >> 1, c = cc & 1;
            int g = gct * 16 + (lane & 15);
            int k = c * 32 + ((lane >> 4) << 3) + j;
            whhp[t] = (f16)gwhh[g * 64 + k];
        }
        else if (idx < S7)   { int t = idx - S6; int k = t >> 8, j = t & 255; s2sihT[t] = swih[j * 128 + k]; }
        else if (idx < S8)   { int t = idx - S7; int k = t >> 8, j = t & 255; s2shhT[t] = swhh[j * 64 + k]; }
        else                 { int t = idx - S8; int k = t >> 8, j = t & 255; memihT[t] = mwih[j * 128 + k]; }
    }
}

// ---------------- prep1: degree ----------------
__global__ void k_prep1(const int* __restrict__ dstp, float* __restrict__ deg)
{
    int e = blockIdx.x * blockDim.x + threadIdx.x;
    if (e < EE) atomicAdd(&deg[dstp[e]], 1.0f);
}

// ---------------- scan: rowptr = exclusive prefix of deg; zero fill ----------------
__global__ __launch_bounds__(1024) void k_scan(const float* __restrict__ deg,
                                               int* __restrict__ rowptr, int* __restrict__ fill)
{
    __shared__ int part[1024];
    const int t = threadIdx.x;
    const int base = t * 20;
    int local[20];
    int s = 0;
#pragma unroll
    for (int j = 0; j < 20; ++j) { local[j] = s; s += (int)deg[base + j]; }
    part[t] = s;
    __syncthreads();
    for (int off = 1; off < 1024; off <<= 1) {
        int u = (t >= off) ? part[t - off] : 0;
        __syncthreads();
        part[t] += u;
        __syncthreads();
    }
    const int coff = part[t] - s;
#pragma unroll
    for (int j = 0; j < 20; ++j) { rowptr[base + j] = coff + local[j]; fill[base + j] = 0; }
    if (t == 1023) rowptr[NN] = part[1023];
}

// ---------------- fill: CSR edge lists ----------------
__global__ void k_fill(const int* __restrict__ dstp, const int* __restrict__ rowptr,
                       int* __restrict__ fill, int* __restrict__ eidx)
{
    int e = blockIdx.x * blockDim.x + threadIdx.x;
    if (e < EE) {
        int d = dstp[e];
        int slot = atomicAdd(&fill[d], 1);
        eidx[rowptr[d] + slot] = e;
    }
}

// ---------------- perm: CSR-order the edge data (once) ----------------
__global__ void k_perm(const int* __restrict__ eidx, const int* __restrict__ srcp,
                       int* __restrict__ sp, const f16* __restrict__ ew16, f16* __restrict__ ewp)
{
    int idx = blockIdx.x * 256 + threadIdx.x;
    if (idx < EE * 64) {
        int r = idx >> 6, c = idx & 63;
        int e = eidx[r];
        ewp[idx] = ew16[((size_t)e << 6) + c];
        if (c == 0) sp[r] = srcp[e];
    }
}

// ---------------- msg GEMM: 64 CSR-ordered edges/block, waves = (K-half x col-half) ----
// Per-block K-rotation ((blockIdx&3)*8 i-steps) spreads L2 demand over B.
__global__ __launch_bounds__(256, 3) void k_msg(const f16* __restrict__ feat16, const f16* __restrict__ ewp,
                                                const f16* __restrict__ qmtp,
                                                const int* __restrict__ sp,
                                                float* __restrict__ msg)
{
    __shared__ f16 s_lds[64 * 64];
    __shared__ f16 w_lds[64 * 64];
    __shared__ float cmb[2][64][36];
    const int tid = threadIdx.x;
    const int e0 = blockIdx.x * 64;
    {
        int row = tid >> 2, q = tid & 3;
        int sn = sp[e0 + row];
        const uint4* gs = (const uint4*)(feat16 + (size_t)sn * 64 + q * 16);
        const uint4* gw = (const uint4*)(ewp + (size_t)(e0 + row) * 64 + q * 16);
        uint4 s0v = gs[0], s1v = gs[1];
        uint4 w0v = gw[0], w1v = gw[1];
        char* sbw = (char*)s_lds;
        char* wbw = (char*)w_lds;
        int swz = (row & 7) << 4;
        *(uint4*)(sbw + row * 128 + ((q * 32) ^ swz)) = s0v;
        *(uint4*)(sbw + row * 128 + ((q * 32 + 16) ^ swz)) = s1v;
        *(uint4*)(wbw + row * 128 + ((q * 32) ^ swz)) = w0v;
        *(uint4*)(wbw + row * 128 + ((q * 32 + 16) ^ swz)) = w1v;
    }
    __syncthreads();
    const int wv = tid >> 6, l = tid & 63;
    const int lh = l >> 4, ll = l & 15;
    const int cp = wv & 1;            // column half (32 cols)
    const int kp = wv >> 1;           // K half
    const int ctb = cp * 2;
    const int rot = (blockIdx.x & 3) << 3;   // K-rotation in i-steps (multiple of 8)
    const char* sb = (const char*)s_lds;
    const char* wb = (const char*)w_lds;
    int rowv[4], swzv[4];
#pragma unroll
    for (int rg = 0; rg < 4; ++rg) { rowv[rg] = rg * 16 + ll; swzv[rg] = (rowv[rg] & 7) << 4; }
    f16x8 wf[4][2];
#pragma unroll
    for (int rg = 0; rg < 4; ++rg) {
        wf[rg][0] = *(const f16x8*)(wb + rowv[rg] * 128 + ((lh * 16) ^ swzv[rg]));
        wf[rg][1] = *(const f16x8*)(wb + rowv[rg] * 128 + ((64 + lh * 16) ^ swzv[rg]));
    }
    const f16x8* base = (const f16x8*)qmtp + l;
    f32x4 acc[4][2] = {};
    const int i0 = kp * 32;
    f16x8 S[3][2][2];                 // 3-deep prefetch ring
#pragma unroll
    for (int pp = 0; pp < 3; ++pp) {
        int ii = i0 + ((pp + rot) & 31);
#pragma unroll
        for (int ab = 0; ab < 2; ++ab)
#pragma unroll
            for (int j = 0; j < 2; ++j)
                S[pp][ab][j] = base[((2 * ii + ab) * 4 + ctb + j) * 64];
    }
    f16x8 sc[4];
#pragma unroll
    for (int p = 0; p < 32; ++p) {
        int ii = i0 + ((p + rot) & 31);
        if ((p & 7) == 0) {
#pragma unroll
            for (int rg = 0; rg < 4; ++rg)
                sc[rg] = *(const f16x8*)(sb + rowv[rg] * 128 + ((ii * 2) ^ swzv[rg]));
        }
        const int bi = p % 3;
        __builtin_amdgcn_s_setprio(1);
#pragma unroll
        for (int rg = 0; rg < 4; ++rg) {
            f16 s = sc[rg][p & 7];
            f16x8 a0, a1;
#pragma unroll
            for (int j8 = 0; j8 < 8; ++j8) { a0[j8] = wf[rg][0][j8] * s; a1[j8] = wf[rg][1][j8] * s; }
#pragma unroll
            for (int j = 0; j < 2; ++j) {
                acc[rg][j] = __builtin_amdgcn_mfma_f32_16x16x32_f16(a0, S[bi][0][j], acc[rg][j], 0, 0, 0);
                acc[rg][j] = __builtin_amdgcn_mfma_f32_16x16x32_f16(a1, S[bi][1][j], acc[rg][j], 0, 0, 0);
            }
        }
        __builtin_amdgcn_s_setprio(0);
        int inext = i0 + (((p + 3) + rot) & 31);
#pragma unroll
        for (int ab = 0; ab < 2; ++ab)
#pragma unroll
            for (int j = 0; j < 2; ++j)
                S[bi][ab][j] = base[((2 * inext + ab) * 4 + ctb + j) * 64];
    }
    if (kp == 1) {
        // bias pair c=128,129 (i=64), loaded fresh: A = feat fragments directly
        f16x8 B0[2], B1[2];
#pragma unroll
        for (int j = 0; j < 2; ++j) {
            B0[j] = base[((2 * 64 + 0) * 4 + ctb + j) * 64];
            B1[j] = base[((2 * 64 + 1) * 4 + ctb + j) * 64];
        }
#pragma unroll
        for (int rg = 0; rg < 4; ++rg) {
            f16x8 sf0 = *(const f16x8*)(sb + rowv[rg] * 128 + ((lh * 16) ^ swzv[rg]));
            f16x8 sf1 = *(const f16x8*)(sb + rowv[rg] * 128 + ((64 + lh * 16) ^ swzv[rg]));
#pragma unroll
            for (int j = 0; j < 2; ++j) {
                acc[rg][j] = __builtin_amdgcn_mfma_f32_16x16x32_f16(sf0, B0[j], acc[rg][j], 0, 0, 0);
                acc[rg][j] = __builtin_amdgcn_mfma_f32_16x16x32_f16(sf1, B1[j], acc[rg][j], 0, 0, 0);
            }
        }
#pragma unroll
        for (int rg = 0; rg < 4; ++rg)
#pragma unroll
            for (int j = 0; j < 2; ++j)
#pragma unroll
                for (int q = 0; q < 4; ++q)
                    cmb[cp][rg * 16 + lh * 4 + q][j * 16 + ll] = acc[rg][j][q];
    }
    __syncthreads();
    if (kp == 0) {
#pragma unroll
        for (int rg = 0; rg < 4; ++rg)
#pragma unroll
            for (int q = 0; q < 4; ++q) {
                int r = rg * 16 + lh * 4 + q;
#pragma unroll
                for (int j = 0; j < 2; ++j) {
                    float v = acc[rg][j][q] + cmb[cp][r][j * 16 + ll];
                    msg[(size_t)(e0 + r) * 64 + ctb * 16 + j * 16 + ll] = v;
                }
            }
    }
}

// ---------------- node update: 16 nodes/block; CONTIGUOUS msg aggregation + MFMA GEMMs ----
__global__ __launch_bounds__(256) void k_node(float* __restrict__ feat, f16* __restrict__ feat16,
        const float* __restrict__ msg, const int* __restrict__ rowptr,
        const float* __restrict__ deg,
        const f16* __restrict__ rootp, const f16* __restrict__ wihp, const f16* __restrict__ whhp,
        const float* __restrict__ conv_b, const float* __restrict__ bih, const float* __restrict__ bhh)
{
    __shared__ f16 h16[16 * 64];
    __shared__ f16 m16[16 * 64];
    __shared__ float aggm[16][68];
    const int tid = threadIdx.x;
    const int wv = tid >> 6, l = tid & 63;
    const int lh = l >> 4, ll = l & 15;
    const int nb = blockIdx.x * 16;
    char* hb = (char*)h16;
    char* mb = (char*)m16;
    // ---- gather: thread (wv,l) aggregates 4 nodes' column l; msg rows are CONTIGUOUS ----
#pragma unroll
    for (int i = 0; i < 4; ++i) {
        int nd = wv * 4 + i;
        int n = nb + nd;
        float hv = feat[(size_t)n * 64 + l];
        int r0 = rowptr[n], r1 = rowptr[n + 1];
        float a = 0.f;
        for (int r = r0; r < r1; ++r) a += msg[(size_t)r * 64 + l];
        aggm[nd][l] = a;
        int swz = (nd & 7) << 4;
        *(f16*)(hb + nd * 128 + ((l * 2) ^ swz)) = (f16)hv;
    }
    __syncthreads();
    const int rsw = (ll & 7) << 4;
    f16x8 hA0 = *(const f16x8*)(hb + ll * 128 + ((lh * 16) ^ rsw));
    f16x8 hA1 = *(const f16x8*)(hb + ll * 128 + ((64 + lh * 16) ^ rsw));
    const int col = wv * 16 + ll;
    float invd[4];
#pragma unroll
    for (int q = 0; q < 4; ++q) invd[q] = 1.0f / fmaxf(deg[nb + lh * 4 + q], 1.0f);
    {
        f16x8 b0 = *(const f16x8*)(rootp + ((size_t)(wv * 2 + 0) * 64 + l) * 8);
        f16x8 b1 = *(const f16x8*)(rootp + ((size_t)(wv * 2 + 1) * 64 + l) * 8);
        f32x4 acc = {};
        acc = __builtin_amdgcn_mfma_f32_16x16x32_f16(hA0, b0, acc, 0, 0, 0);
        acc = __builtin_amdgcn_mfma_f32_16x16x32_f16(hA1, b1, acc, 0, 0, 0);
        float cb = conv_b[col];
#pragma unroll
        for (int q = 0; q < 4; ++q) {
            int row = lh * 4 + q;
            float mv = fmaxf(aggm[row][col] * invd[q] + acc[q] + cb, 0.f);
            int swz = (row & 7) << 4;
            *(f16*)(mb + row * 128 + ((col * 2) ^ swz)) = (f16)mv;
        }
    }
    __syncthreads();
    f16x8 mA0 = *(const f16x8*)(mb + ll * 128 + ((lh * 16) ^ rsw));
    f16x8 mA1 = *(const f16x8*)(mb + ll * 128 + ((64 + lh * 16) ^ rsw));
    f32x4 gi0 = {}, gi1 = {}, gi2 = {}, gh0 = {}, gh1 = {}, gh2 = {};
    {
        f16x8 b;
        b = *(const f16x8*)(wihp + ((size_t)((wv + 0) * 2 + 0) * 64 + l) * 8);
        gi0 = __builtin_amdgcn_mfma_f32_16x16x32_f16(mA0, b, gi0, 0, 0, 0);
        b = *(const f16x8*)(wihp + ((size_t)((wv + 0) * 2 + 1) * 64 + l) * 8);
        gi0 = __builtin_amdgcn_mfma_f32_16x16x32_f16(mA1, b, gi0, 0, 0, 0);
        b = *(const f16x8*)(wihp + ((size_t)((wv + 4) * 2 + 0) * 64 + l) * 8);
        gi1 = __builtin_amdgcn_mfma_f32_16x16x32_f16(mA0, b, gi1, 0, 0, 0);
        b = *(const f16x8*)(wihp + ((size_t)((wv + 4) * 2 + 1) * 64 + l) * 8);
        gi1 = __builtin_amdgcn_mfma_f32_16x16x32_f16(mA1, b, gi1, 0, 0, 0);
        b = *(const f16x8*)(wihp + ((size_t)((wv + 8) * 2 + 0) * 64 + l) * 8);
        gi2 = __builtin_amdgcn_mfma_f32_16x16x32_f16(mA0, b, gi2, 0, 0, 0);
        b = *(const f16x8*)(wihp + ((size_t)((wv + 8) * 2 + 1) * 64 + l) * 8);
        gi2 = __builtin_amdgcn_mfma_f32_16x16x32_f16(mA1, b, gi2, 0, 0, 0);
        b = *(const f16x8*)(whhp + ((size_t)((wv + 0) * 2 + 0) * 64 + l) * 8);
        gh0 = __builtin_amdgcn_mfma_f32_16x16x32_f16(hA0, b, gh0, 0, 0, 0);
        b = *(const f16x8*)(whhp + ((size_t)((wv + 0) * 2 + 1) * 64 + l) * 8);
        gh0 = __builtin_amdgcn_mfma_f32_16x16x32_f16(hA1, b, gh0, 0, 0, 0);
        b = *(const f16x8*)(whhp + ((size_t)((wv + 4) * 2 + 0) * 64 + l) * 8);
        gh1 = __builtin_amdgcn_mfma_f32_16x16x32_f16(hA0, b, gh1, 0, 0, 0);
        b = *(const f16x8*)(whhp + ((size_t)((wv + 4) * 2 + 1) * 64 + l) * 8);
        gh1 = __builtin_amdgcn_mfma_f32_16x16x32_f16(hA1, b, gh1, 0, 0, 0);
        b = *(const f16x8*)(whhp + ((size_t)((wv + 8) * 2 + 0) * 64 + l) * 8);
        gh2 = __builtin_amdgcn_mfma_f32_16x16x32_f16(hA0, b, gh2, 0, 0, 0);
        b = *(const f16x8*)(whhp + ((size_t)((wv + 8) * 2 + 1) * 64 + l) * 8);
        gh2 = __builtin_amdgcn_mfma_f32_16x16x32_f16(hA1, b, gh2, 0, 0, 0);
    }
    {
        float bi0 = bih[col], bi1 = bih[64 + col], bi2 = bih[128 + col];
        float bh0 = bhh[col], bh1 = bhh[64 + col], bh2 = bhh[128 + col];
#pragma unroll
        for (int q = 0; q < 4; ++q) {
            int n = nb + lh * 4 + q;
            float r = sigm(gi0[q] + bi0 + gh0[q] + bh0);
            float z = sigm(gi1[q] + bi1 + gh1[q] + bh1);
            float nn2 = tanh_f(gi2[q] + bi2 + r * (gh2[q] + bh2));
            float hold = feat[(size_t)n * 64 + col];
            float hn = (1.f - z) * nn2 + z * hold;
            feat[(size_t)n * 64 + col] = hn;
            feat16[(size_t)n * 64 + col] = (f16)hn;
        }
    }
}

// ---------------- Set2Set (6 steps) + memory LSTM; 2 graphs/block, 512 threads, K-split gates ----
__global__ __launch_bounds__(512) void k_s2s(const float* __restrict__ feat,
                                             const float* __restrict__ s2sihT, const float* __restrict__ s2shhT,
                                             const float* __restrict__ sbih, const float* __restrict__ sbhh,
                                             const float* __restrict__ memihT,
                                             const float* __restrict__ mbih, const float* __restrict__ mbhh,
                                             float* __restrict__ lstm_out, float* __restrict__ dout)
{
    __shared__ float ft[2][64][49];
    __shared__ float qs[2][128];
    __shared__ float hh[2][64];
    __shared__ float cc[2][64];
    __shared__ float qv[2][64];
    __shared__ float g0p[2][256];
    __shared__ float g1p[2][256];
    const int t = threadIdx.x;
    const int g0 = blockIdx.x * 2;
    for (int i = t; i < 2 * 40 * 64; i += 512) {
        int g = i / 2560;
        int rem = i - g * 2560;
        int row = rem >> 6, o = rem & 63;
        ft[g][o][row] = feat[((size_t)(g0 + g) * 40 + row) * 64 + o];
    }
    if (t < 256) qs[t >> 7][t & 127] = 0.f;
    if (t < 128) { hh[t >> 6][t & 63] = 0.f; cc[t >> 6][t & 63] = 0.f; }
    __syncthreads();
    const int jj = t & 255;
    const int half = t >> 8;
    const int gg = t >> 6, gl = t & 63;
    const float b_s = sbih[jj] + sbhh[jj];
    const float b_m = mbih[jj] + mbhh[jj];
    for (int step = 0; step < 7; ++step) {
        const bool mem = (step == 6);
        {
            float a0, a1;
            if (!mem) {
                if (half == 0) {
                    a0 = b_s; a1 = b_s;
#pragma unroll 16
                    for (int k = 0; k < 96; ++k) {
                        float w = s2sihT[k * 256 + jj];
                        a0 += qs[0][k] * w;
                        a1 += qs[1][k] * w;
                    }
                } else {
                    a0 = 0.f; a1 = 0.f;
#pragma unroll 16
                    for (int k = 96; k < 128; ++k) {
                        float w = s2sihT[k * 256 + jj];
                        a0 += qs[0][k] * w;
                        a1 += qs[1][k] * w;
                    }
#pragma unroll 16
                    for (int k = 0; k < 64; ++k) {
                        float w = s2shhT[k * 256 + jj];
                        a0 += hh[0][k] * w;
                        a1 += hh[1][k] * w;
                    }
                }
            } else {
                if (half == 0) {
                    a0 = b_m; a1 = b_m;
#pragma unroll 16
                    for (int k = 0; k < 64; ++k) {
                        float w = memihT[k * 256 + jj];
                        a0 += qs[0][k] * w;
                        a1 += qs[1][k] * w;
                    }
                } else {
                    a0 = 0.f; a1 = 0.f;
#pragma unroll 16
                    for (int k = 64; k < 128; ++k) {
                        float w = memihT[k * 256 + jj];
                        a0 += qs[0][k] * w;
                        a1 += qs[1][k] * w;
                    }
                }
            }
            if (half == 0) { g0p[0][jj] = a0; g0p[1][jj] = a1; }
            else           { g1p[0][jj] = a0; g1p[1][jj] = a1; }
        }
        __syncthreads();
        if (t < 128) {
            float ii = sigm(g0p[gg][gl]        + g1p[gg][gl]);
            float ff = sigm(g0p[gg][64 + gl]   + g1p[gg][64 + gl]);
            float g2 = tanh_f(g0p[gg][128 + gl] + g1p[gg][128 + gl]);
            float oo = sigm(g0p[gg][192 + gl]  + g1p[gg][192 + gl]);
            float cprev = mem ? 0.f : cc[gg][gl];
            float c2 = ff * cprev + ii * g2;
            float h2 = oo * tanh_f(c2);
            if (!mem) {
                cc[gg][gl] = c2; hh[gg][gl] = h2;
                qv[gg][gl] = h2; qs[gg][gl] = h2;
                const int g = gg, l = gl;
                float e = -1e30f;
                if (l < 40) {
                    float s = 0.f;
                    for (int o = 0; o < 64; ++o) s += ft[g][o][l] * qv[g][o];
                    e = s;
                }
                float emax = e;
#pragma unroll
                for (int off = 32; off; off >>= 1) emax = fmaxf(emax, __shfl_xor(emax, off));
                float av = (l < 40) ? __expf(e - emax) : 0.f;
                float asum = av;
#pragma unroll
                for (int off = 32; off; off >>= 1) asum += __shfl_xor(asum, off);
                av /= asum;
                float r = 0.f;
                for (int nd = 0; nd < 40; ++nd) r += __shfl(av, nd) * ft[g][l][nd];
                qs[g][64 + l] = r;
            } else {
                int gidx = g0 + gg;
                lstm_out[(size_t)gidx * 64 + gl] = h2;
                dout[18432 + (size_t)gidx * 64 + gl] = h2;
                dout[18432 + 32768 + (size_t)gidx * 64 + gl] = c2;
            }
        }
        __syncthreads();
    }
}

// ---------------- final MLP with the reference's (d,a,s) scramble ----------------
__global__ __launch_bounds__(256) void k_final(const float* __restrict__ feat,
                                               const float* __restrict__ lstm_out,
                                               const int* __restrict__ nrbidx, const int* __restrict__ nonring,
                                               const float* __restrict__ l1w, const float* __restrict__ l1b,
                                               const float* __restrict__ l2w, const float* __restrict__ l2b,
                                               float* __restrict__ dout)
{
    __shared__ float z_lds[4][320];
    __shared__ float y_lds[4][64];
    const int wv = threadIdx.x >> 6, l = threadIdx.x & 63;
    const int r = blockIdx.x * 4 + wv;
    const int b = r / 6, rr = r - b * 6;
#pragma unroll
    for (int p = 0; p < 5; ++p) {
        int c = p * 64 + l;
        int f2 = rr * 320 + c;
        int d = f2 / 30;
        int rem = f2 - d * 30;
        int a = rem / 5;
        int s = rem - a * 5;
        float v;
        if (s == 0) v = lstm_out[(size_t)nrbidx[b * 6 + a] * 64 + d];
        else {
            int atom = nonring[b * 24 + (s - 1) * 6 + a];
            v = feat[(size_t)atom * 64 + d];
        }
        z_lds[wv][c] = v;
    }
    __syncthreads();
    {
        float acc = l1b[l];
        const float4* wr = (const float4*)(l1w + (size_t)l * 320);
        const float4* zr = (const float4*)(z_lds[wv]);
        for (int c4 = 0; c4 < 80; ++c4) {
            float4 w4 = wr[c4]; float4 z4 = zr[c4];
            acc += w4.x * z4.x + w4.y * z4.y + w4.z * z4.z + w4.w * z4.w;
        }
        y_lds[wv][l] = fmaxf(acc, 0.f);
    }
    __syncthreads();
    if (l < 6) {
        float acc = l2b[l];
        const float* yr = y_lds[wv];
        const float* w2 = l2w + l * 64;
        for (int o = 0; o < 64; ++o) acc += yr[o] * w2[o];
        dout[b * 36 + rr * 6 + l] = acc;
    }
}

extern "C" void kernel_launch(void* const* d_in, const int* in_sizes, int n_in,
                              void* d_out, int out_size, void* d_ws, size_t ws_size,
                              hipStream_t stream)
{
    const float* x    = (const float*)d_in[0];
    const float* ea   = (const float*)d_in[1];
    const int*   ei   = (const int*)d_in[2];
    const int*   nrb  = (const int*)d_in[4];
    const int*   nonr = (const int*)d_in[5];
    const float* l0w  = (const float*)d_in[6];  const float* l0b = (const float*)d_in[7];
    const float* e1w  = (const float*)d_in[8];  const float* e1b = (const float*)d_in[9];
    const float* e2w  = (const float*)d_in[10]; const float* e2b = (const float*)d_in[11];
    const float* rootw= (const float*)d_in[12]; const float* convb = (const float*)d_in[13];
    const float* gwih = (const float*)d_in[14]; const float* gbih = (const float*)d_in[15];
    const float* gwhh = (const float*)d_in[16]; const float* gbhh = (const float*)d_in[17];
    const float* swih = (const float*)d_in[18]; const float* sbih = (const float*)d_in[19];
    const float* swhh = (const float*)d_in[20]; const float* sbhh = (const float*)d_in[21];
    const float* mwih = (const float*)d_in[22]; const float* mbih = (const float*)d_in[23];
    const float* mbhh = (const float*)d_in[25];
    const float* l1w  = (const float*)d_in[26]; const float* l1b = (const float*)d_in[27];
    const float* l2w  = (const float*)d_in[28]; const float* l2b = (const float*)d_in[29];
    const int* srcp = ei;
    const int* dstp = ei + EE;
    float* dout = (float*)d_out;

    char* w = (char*)d_ws;
    size_t off = 0;
    auto alloc = [&](size_t bytes) -> void* {
        off = (off + 255) & ~(size_t)255;
        void* p = w + off;
        off += bytes;
        return p;
    };
    float* feat    = (float*)alloc((size_t)NN * 64 * 4);
    f16*   feat16  = (f16*)alloc((size_t)NN * 64 * 2);
    f16*   ew16    = (f16*)alloc((size_t)EE * 64 * 2);
    f16*   ewp     = (f16*)alloc((size_t)EE * 64 * 2);
    f16*   qmtp    = (f16*)alloc((size_t)136 * 256 * 8 * 2);
    float* msg     = (float*)alloc((size_t)EE * 64 * 4);
    float* deg     = (float*)alloc((size_t)NN * 4);
    int*   rowptr  = (int*)alloc((size_t)(NN + 1) * 4);
    int*   fill    = (int*)alloc((size_t)NN * 4);
    int*   eidx    = (int*)alloc((size_t)EE * 4);
    int*   sp      = (int*)alloc((size_t)EE * 4);
    f16*   rootp   = (f16*)alloc((size_t)4096 * 2);
    f16*   wihp    = (f16*)alloc((size_t)12288 * 2);
    f16*   whhp    = (f16*)alloc((size_t)12288 * 2);
    float* s2sihT  = (float*)alloc((size_t)128 * 256 * 4);
    float* s2shhT  = (float*)alloc((size_t)64 * 256 * 4);
    float* memihT  = (float*)alloc((size_t)128 * 256 * 4);
    float* lstmo   = (float*)alloc((size_t)BB * 64 * 4);
    (void)ws_size; (void)in_sizes; (void)n_in; (void)out_size;

    hipLaunchKernelGGL(k_prep0, dim3(1024), dim3(256), 0, stream,
                       x, ea, l0w, l0b, e1w, e1b, e2w, e2b, rootw, gwih, gwhh, swih, swhh, mwih,
                       feat, feat16, ew16, qmtp, deg, rootp, wihp, whhp, s2sihT, s2shhT, memihT);
    hipLaunchKernelGGL(k_prep1, dim3(EE / 256), dim3(256), 0, stream, dstp, deg);
    hipLaunchKernelGGL(k_scan, dim3(1), dim3(1024), 0, stream, deg, rowptr, fill);
    hipLaunchKernelGGL(k_fill, dim3(EE / 256), dim3(256), 0, stream, dstp, rowptr, fill, eidx);
    hipLaunchKernelGGL(k_perm, dim3(EE * 64 / 256), dim3(256), 0, stream, eidx, srcp, sp, ew16, ewp);
    for (int it = 0; it < 6; ++it) {
        hipLaunchKernelGGL(k_msg, dim3(EE / 64), dim3(256), 0, stream,
                           feat16, ewp, qmtp, sp, msg);
        hipLaunchKernelGGL(k_node, dim3(NN / 16), dim3(256), 0, stream,
                           feat, feat16, msg, rowptr, deg, rootp, wihp, whhp, convb, gbih, gbhh);
    }
    hipLaunchKernelGGL(k_s2s, dim3(BB / 2), dim3(512), 0, stream,
                       feat, s2sihT, s2shhT, sbih, sbhh, memihT, mbih, mbhh, lstmo, dout);
    hipLaunchKernelGGL(k_final, dim3(TT / 4), dim3(256), 0, stream,
                       feat, lstmo, nrb, nonr, l1w, l1b, l2w, l2b, dout);
}